// Round 2
// baseline (276.745 us; speedup 1.0000x reference)
//
#include <hip/hip_runtime.h>

#define THREADS 256
#define ROWS_PER_BLOCK 1024           // 4 rows per thread
#define ELEMS_PER_BLOCK (ROWS_PER_BLOCK * 9)   // 9216 floats = 36 KB LDS

__global__ __launch_bounds__(THREADS) void ce_main_kernel(
    const float* __restrict__ logits,
    const int*   __restrict__ target,
    const float* __restrict__ cw,
    float*       __restrict__ acc,   // acc[0] = loss sum, acc[1] = nonzero count
    int N)
{
    __shared__ float lds[ELEMS_PER_BLOCK];
    __shared__ float wsh[9];
    __shared__ float rsum[4];
    __shared__ int   rcnt[4];

    const int t = threadIdx.x;
    const int rowBase  = blockIdx.x * ROWS_PER_BLOCK;
    const int elemBase = rowBase * 9;                 // < 36M, fits int
    const int totalElems = N * 9;

    if (t < 9) wsh[t] = cw[t];

    if (elemBase + ELEMS_PER_BLOCK <= totalElems) {
        // full block: coalesced float4 staging (16 B/lane, 9 iters)
        const float4* __restrict__ src = (const float4*)(logits + elemBase);
        float4* __restrict__ dst = (float4*)lds;
        #pragma unroll
        for (int k = 0; k < 9; ++k)
            dst[t + k * THREADS] = src[t + k * THREADS];
    } else {
        // tail block: scalar bounds-checked staging
        for (int k = 0; k < ELEMS_PER_BLOCK / THREADS; ++k) {
            int i = t + k * THREADS;
            int g = elemBase + i;
            lds[i] = (g < totalElems) ? logits[g] : 0.0f;
        }
    }
    __syncthreads();

    float lsum = 0.0f;
    int   lcnt = 0;

    #pragma unroll
    for (int j = 0; j < ROWS_PER_BLOCK / THREADS; ++j) {
        const int lr  = t + j * THREADS;       // local row; stride-256 keeps LDS reads 2-way (free)
        const int row = rowBase + lr;
        if (row < N) {
            const float* __restrict__ x = &lds[lr * 9];
            float m = x[0];
            #pragma unroll
            for (int k = 1; k < 9; ++k) m = fmaxf(m, x[k]);
            float s = 0.0f;
            #pragma unroll
            for (int k = 0; k < 9; ++k) s += __expf(x[k] - m);
            const int tg = target[row];
            const float lp = x[tg] - m - __logf(s);
            const float loss = -wsh[tg] * lp;
            lsum += loss;
            lcnt += (loss > 1e-16f) ? 1 : 0;
        }
    }

    // wave (64-lane) shuffle reduction
    #pragma unroll
    for (int off = 32; off > 0; off >>= 1) {
        lsum += __shfl_down(lsum, off);
        lcnt += __shfl_down(lcnt, off);
    }
    const int wave = t >> 6;
    const int lane = t & 63;
    if (lane == 0) { rsum[wave] = lsum; rcnt[wave] = lcnt; }
    __syncthreads();
    if (t == 0) {
        const float bs = rsum[0] + rsum[1] + rsum[2] + rsum[3];
        const int   bc = rcnt[0] + rcnt[1] + rcnt[2] + rcnt[3];
        atomicAdd(&acc[0], bs);
        atomicAdd(&acc[1], (float)bc);   // count <= 4M: exact in fp32
    }
}

__global__ void ce_finalize_kernel(const float* __restrict__ acc,
                                   float* __restrict__ out, int N)
{
    const float S = acc[0];
    const float C = acc[1];
    out[0] = S / (C + 1e-16f);   // nonzero-mean
    out[1] = S / (float)N;       // plain mean
}

extern "C" void kernel_launch(void* const* d_in, const int* in_sizes, int n_in,
                              void* d_out, int out_size, void* d_ws, size_t ws_size,
                              hipStream_t stream) {
    const float* logits = (const float*)d_in[0];
    const int*   target = (const int*)d_in[1];
    const float* cw     = (const float*)d_in[2];
    float* out = (float*)d_out;
    float* acc = (float*)d_ws;

    const int N = in_sizes[1];   // number of rows (target element count)

    // zero the two accumulators (d_ws is re-poisoned to 0xAA before every launch)
    hipMemsetAsync(acc, 0, 2 * sizeof(float), stream);

    const int grid = (N + ROWS_PER_BLOCK - 1) / ROWS_PER_BLOCK;
    ce_main_kernel<<<grid, THREADS, 0, stream>>>(logits, target, cw, acc, N);
    ce_finalize_kernel<<<1, 1, 0, stream>>>(acc, out, N);
}

// Round 4
// 216.166 us; speedup vs baseline: 1.2802x; 1.2802x over previous
//
#include <hip/hip_runtime.h>

#define THREADS 256
#define MAX_GRID 2048

// float4 with 4-byte alignment: rows are 36 B apart, so only 4-B aligned.
// gfx950 supports HW-unaligned global loads; this emits global_load_dwordx4.
typedef float f4 __attribute__((ext_vector_type(4)));
struct f4u { f4 v; } __attribute__((packed, aligned(4)));

__global__ __launch_bounds__(THREADS) void ce_main_kernel(
    const float* __restrict__ logits,
    const int*   __restrict__ target,
    const float* __restrict__ cw,
    float2*      __restrict__ partials,   // one (sum,count) pair per block
    int N)
{
    __shared__ float rsum[THREADS / 64];
    __shared__ float rcnt[THREADS / 64];

    const int t      = threadIdx.x;
    const int tid    = blockIdx.x * THREADS + t;
    const int stride = gridDim.x * THREADS;

    float lsum = 0.0f;
    float lcnt = 0.0f;

    for (int r = tid; r < N; r += stride) {
        const int tg = target[r];
        const float* __restrict__ row = logits + (size_t)r * 9;
        // issue all loads up front (independent; overlap HBM latency)
        const f4u* p = (const f4u*)row;
        const f4 a = p[0].v;            // x[0..3]
        const f4 b = p[1].v;            // x[4..7]
        const float c = row[8];
        const float xt = row[tg];       // L1-hit gather (line just fetched); avoids scratch array
        const float w  = cw[tg];        // 36-B table, L1-hot

        float m = fmaxf(fmaxf(fmaxf(a.x, a.y), fmaxf(a.z, a.w)),
                        fmaxf(fmaxf(b.x, b.y), fmaxf(b.z, b.w)));
        m = fmaxf(m, c);
        float s = __expf(a.x - m) + __expf(a.y - m) + __expf(a.z - m) + __expf(a.w - m)
                + __expf(b.x - m) + __expf(b.y - m) + __expf(b.z - m) + __expf(b.w - m)
                + __expf(c - m);
        const float loss = -w * (xt - m - __logf(s));
        lsum += loss;
        lcnt += (loss > 1e-16f) ? 1.0f : 0.0f;
    }

    // 64-lane wave reduction
    #pragma unroll
    for (int off = 32; off > 0; off >>= 1) {
        lsum += __shfl_down(lsum, off);
        lcnt += __shfl_down(lcnt, off);
    }
    const int wave = t >> 6;
    if ((t & 63) == 0) { rsum[wave] = lsum; rcnt[wave] = lcnt; }
    __syncthreads();
    if (t == 0) {
        float bs = 0.0f, bc = 0.0f;
        #pragma unroll
        for (int w2 = 0; w2 < THREADS / 64; ++w2) { bs += rsum[w2]; bc += rcnt[w2]; }
        partials[blockIdx.x] = make_float2(bs, bc);   // no atomics
    }
}

__global__ __launch_bounds__(THREADS) void ce_finalize_kernel(
    const float2* __restrict__ partials, float* __restrict__ out,
    int nPartials, float invN)
{
    __shared__ float rsum[THREADS / 64];
    __shared__ float rcnt[THREADS / 64];
    const int t = threadIdx.x;
    float s = 0.0f, c = 0.0f;
    for (int i = t; i < nPartials; i += THREADS) {
        const float2 p = partials[i];
        s += p.x; c += p.y;
    }
    #pragma unroll
    for (int off = 32; off > 0; off >>= 1) {
        s += __shfl_down(s, off);
        c += __shfl_down(c, off);
    }
    const int wave = t >> 6;
    if ((t & 63) == 0) { rsum[wave] = s; rcnt[wave] = c; }
    __syncthreads();
    if (t == 0) {
        float S = 0.0f, C = 0.0f;
        #pragma unroll
        for (int w2 = 0; w2 < THREADS / 64; ++w2) { S += rsum[w2]; C += rcnt[w2]; }
        out[0] = S / (C + 1e-16f);   // mean over nonzero losses
        out[1] = S * invN;           // plain mean
    }
}

extern "C" void kernel_launch(void* const* d_in, const int* in_sizes, int n_in,
                              void* d_out, int out_size, void* d_ws, size_t ws_size,
                              hipStream_t stream) {
    const float* logits = (const float*)d_in[0];
    const int*   target = (const int*)d_in[1];
    const float* cw     = (const float*)d_in[2];
    float* out = (float*)d_out;
    float2* partials = (float2*)d_ws;

    const int N = in_sizes[1];   // row count (target element count)

    int grid = MAX_GRID;
    const int maxByWs = (int)(ws_size / sizeof(float2));
    if (grid > maxByWs) grid = maxByWs;           // stay inside scratch
    const int maxByN = (N + THREADS - 1) / THREADS;
    if (grid > maxByN) grid = maxByN;

    ce_main_kernel<<<grid, THREADS, 0, stream>>>(logits, target, cw, partials, N);
    ce_finalize_kernel<<<1, THREADS, 0, stream>>>(partials, out, grid, 1.0f / (float)N);
}